// Round 5
// baseline (1143.368 us; speedup 1.0000x reference)
//
#include <hip/hip_runtime.h>

// GCN: N=100000 nodes, E=3200000 edges, dims 8 -> 64 -> 64 -> 112
//
// Algebra: per layer  agg[i] = hs[i] + sum_{j->i} hs[j]   (hs pre-scaled by dinv)
//                     t      = (dinv[i]*agg[i]) @ W + b
//                     hs_out = relu(t)*dinv[i]  (final layer: t raw)
// Layer 1 aggregates the 8-dim input; layers 2/3 aggregate 64-dim states.
//
// CSR build: bucket edges by dst>>7 into contiguous segments (clustered u32x2
// append), per-bucket LDS histogram -> node degrees (coalesced), proven global
// scan chain -> row_start/cursor/dinv, then a linear bucket-ordered placement
// pass whose cursor atomics and csr_src writes are L2-clustered.

#define NNODES 100000
#define NEDGES 3200000
#define BW     128                          // nodes per bucket (dst >> 7)
#define NB     ((NNODES + BW - 1) / BW)     // 782 buckets
#define PAD    16                           // counter stride (ints) = 64B line
#define NBLK   ((NNODES + 255) / 256)       // 391 scan blocks

// ---------------- CSR build ----------------

__global__ void bzero_kernel(int* __restrict__ bcnt) {
    int i = blockIdx.x * blockDim.x + threadIdx.x;
    if (i < NB * PAD) bcnt[i] = 0;
}

__global__ void bcount_kernel(const int* __restrict__ dst, int* __restrict__ bcnt) {
    int e = blockIdx.x * blockDim.x + threadIdx.x;
    if (e < NEDGES) atomicAdd(&bcnt[(dst[e] >> 7) * PAD], 1);
}

// single-block exclusive scan of NB bucket counts -> bstart, bcur
__global__ void bscan_kernel(const int* __restrict__ bcnt, int* __restrict__ bstart,
                             int* __restrict__ bcur) {
    __shared__ int sh[1024];
    int v = (threadIdx.x < NB) ? bcnt[threadIdx.x * PAD] : 0;
    sh[threadIdx.x] = v;
    __syncthreads();
    for (int off = 1; off < 1024; off <<= 1) {
        int t = (threadIdx.x >= off) ? sh[threadIdx.x - off] : 0;
        __syncthreads();
        sh[threadIdx.x] += t;
        __syncthreads();
    }
    if (threadIdx.x < NB) {
        int e = sh[threadIdx.x] - v;       // exclusive
        bstart[threadIdx.x] = e;
        bcur[threadIdx.x * PAD] = e;
    }
    if (threadIdx.x == 0) bstart[NB] = NEDGES;
}

// append (dst,src) into the bucket's contiguous segment; writes cluster
__global__ void bfill_kernel(const int* __restrict__ src, const int* __restrict__ dst,
                             int* __restrict__ bcur,
                             int* __restrict__ tmp_dst, int* __restrict__ tmp_src) {
    int e = blockIdx.x * blockDim.x + threadIdx.x;
    if (e < NEDGES) {
        int d = dst[e];
        int p = atomicAdd(&bcur[(d >> 7) * PAD], 1);
        tmp_dst[p] = d;
        tmp_src[p] = src[e];
    }
}

// one block per bucket: LDS histogram of the bucket segment -> coalesced cnt[]
__global__ void bhist_kernel(const int* __restrict__ tmp_dst, const int* __restrict__ bstart,
                             int* __restrict__ cnt) {
    __shared__ int c[BW];
    int b   = blockIdx.x;
    int lo  = b * BW;
    int beg = bstart[b], end = bstart[b + 1];

    for (int t = threadIdx.x; t < BW; t += blockDim.x) c[t] = 0;
    __syncthreads();
    for (int k = beg + threadIdx.x; k < end; k += blockDim.x)
        atomicAdd(&c[tmp_dst[k] - lo], 1);
    __syncthreads();
    for (int t = threadIdx.x; t < BW; t += blockDim.x) {
        int i = lo + t;
        if (i < NNODES) cnt[i] = c[t];
    }
}

// ---- proven scan chain (round 2/3) ----

// per-block exclusive scan; block sums out
__global__ void scan1_kernel(const int* __restrict__ cnt, int* __restrict__ excl,
                             int* __restrict__ bsum) {
    __shared__ int sh[256];
    int i = blockIdx.x * 256 + threadIdx.x;
    int v = (i < NNODES) ? cnt[i] : 0;
    sh[threadIdx.x] = v;
    __syncthreads();
    for (int off = 1; off < 256; off <<= 1) {
        int t = (threadIdx.x >= off) ? sh[threadIdx.x - off] : 0;
        __syncthreads();
        sh[threadIdx.x] += t;
        __syncthreads();
    }
    if (i < NNODES) excl[i] = sh[threadIdx.x] - v;   // exclusive
    if (threadIdx.x == 255) bsum[blockIdx.x] = sh[255];
}

// single-block exclusive scan of the 391 block sums
__global__ void scan2_kernel(int* __restrict__ bsum) {
    __shared__ int sh[512];
    int v = (threadIdx.x < NBLK) ? bsum[threadIdx.x] : 0;
    sh[threadIdx.x] = v;
    __syncthreads();
    for (int off = 1; off < 512; off <<= 1) {
        int t = (threadIdx.x >= off) ? sh[threadIdx.x - off] : 0;
        __syncthreads();
        sh[threadIdx.x] += t;
        __syncthreads();
    }
    if (threadIdx.x < NBLK) bsum[threadIdx.x] = sh[threadIdx.x] - v;
}

// add block offsets; init cursor; set row_start[N]; dinv = rsqrt(cnt+1)
__global__ void scan3_kernel(int* __restrict__ row_start, const int* __restrict__ bsum,
                             int* __restrict__ cursor, const int* __restrict__ cnt,
                             float* __restrict__ dinv) {
    int i = blockIdx.x * 256 + threadIdx.x;
    if (i < NNODES) {
        int r = row_start[i] + bsum[blockIdx.x];
        row_start[i] = r;
        cursor[i] = r;
        dinv[i] = rsqrtf((float)cnt[i] + 1.0f);
    }
    if (i == 0) row_start[NNODES] = NEDGES;
}

// linear pass over bucket-ordered edges: cursor atomics + csr writes are clustered
__global__ void place_kernel(const int* __restrict__ tmp_dst, const int* __restrict__ tmp_src,
                             int* __restrict__ cursor, int* __restrict__ csr_src) {
    int e = blockIdx.x * blockDim.x + threadIdx.x;
    if (e < NEDGES) {
        int d = tmp_dst[e];
        int pos = atomicAdd(&cursor[d], 1);
        csr_src[pos] = tmp_src[e];
    }
}

// ---------------- GCN layers ----------------

// xs[i][:] = x[i][:] * dinv[i]   (8 floats per node = 2 float4)
__global__ void prescale_kernel(const float* __restrict__ x, const float* __restrict__ dinv,
                                float* __restrict__ xs) {
    int idx = blockIdx.x * blockDim.x + threadIdx.x;
    if (idx >= NNODES * 2) return;
    float di = dinv[idx >> 1];
    float4 v = ((const float4*)x)[idx];
    v.x *= di; v.y *= di; v.z *= di; v.w *= di;
    ((float4*)xs)[idx] = v;
}

// agg[i][:] = hs[i][:] + sum_{j in N(i)} hs[j][:]  (thread owns one float4)
template<int F>
__global__ void gather_kernel(const float* __restrict__ hs, const int* __restrict__ row_start,
                              const int* __restrict__ csr_src, float* __restrict__ agg) {
    constexpr int NQ = F / 4;
    int idx = blockIdx.x * blockDim.x + threadIdx.x;
    if (idx >= NNODES * NQ) return;
    int i = idx / NQ;
    int q = idx % NQ;

    const float4* t4 = (const float4*)hs;
    float4 acc = t4[i * NQ + q];              // self-loop
    int beg = row_start[i], end = row_start[i + 1];
    for (int k = beg; k < end; ++k) {
        int s = csr_src[k];
        float4 v = t4[s * NQ + q];
        acc.x += v.x; acc.y += v.y; acc.z += v.z; acc.w += v.w;
    }
    ((float4*)agg)[i * NQ + q] = acc;
}

// out[i][f] = post( dinv[i] * (agg[i][:] @ W[:][f]) + b[f] )
template<int FIN, int FOUT, bool RELU, bool SCALE>
__global__ void transform_kernel(const float* __restrict__ agg, const float* __restrict__ dinv,
                                 const float* __restrict__ W, const float* __restrict__ b,
                                 float* __restrict__ out) {
    __shared__ float Ws[FIN * FOUT];
    __shared__ float bs[FOUT];
    for (int t = threadIdx.x; t < FIN * FOUT; t += blockDim.x) Ws[t] = W[t];
    for (int t = threadIdx.x; t < FOUT; t += blockDim.x) bs[t] = b[t];
    __syncthreads();

    int idx = blockIdx.x * blockDim.x + threadIdx.x;
    if (idx >= NNODES * FOUT) return;
    int i = idx / FOUT;   // compile-time divisor -> magic multiply
    int f = idx % FOUT;

    const float* row = agg + i * FIN;
    float sum = 0.f;
#pragma unroll
    for (int k = 0; k < FIN; ++k) sum += row[k] * Ws[k * FOUT + f];

    float di = dinv[i];
    float v = sum * di + bs[f];
    if (RELU)  v = fmaxf(v, 0.f);
    if (SCALE) v *= di;
    out[idx] = v;
}

extern "C" void kernel_launch(void* const* d_in, const int* in_sizes, int n_in,
                              void* d_out, int out_size, void* d_ws, size_t ws_size,
                              hipStream_t stream) {
    const float* x  = (const float*)d_in[0];
    const int*   ei = (const int*)d_in[1];
    const float* W1 = (const float*)d_in[2];
    const float* b1 = (const float*)d_in[3];
    const float* W2 = (const float*)d_in[4];
    const float* b2 = (const float*)d_in[5];
    const float* W3 = (const float*)d_in[6];
    const float* b3 = (const float*)d_in[7];

    const int* src = ei;            // edge_index[0]
    const int* dst = ei + NEDGES;   // edge_index[1]

    float* out = (float*)d_out;     // N*112

    // workspace layout (16B-aligned chunks). tmp_dst/tmp_src alias bufG
    // (25.6MB each side): tmp is dead before the first 64-dim gather writes bufG.
    char* w = (char*)d_ws;
    int*   bcnt      = (int*)w;                    w += NB * PAD * 4;
    int*   bcur      = (int*)w;                    w += NB * PAD * 4;
    int*   bstart    = (int*)w;                    w += ((NB + 1 + 3) / 4) * 16;
    int*   cnt       = (int*)w;                    w += ((NNODES + 3) / 4) * 16;
    int*   row_start = (int*)w;                    w += ((NNODES + 1 + 3) / 4) * 16;
    int*   cursor    = (int*)w;                    w += ((NNODES + 3) / 4) * 16;
    int*   bsum      = (int*)w;                    w += 512 * 4;
    float* dinv      = (float*)w;                  w += ((NNODES + 3) / 4) * 16;
    int*   csr_src   = (int*)w;                    w += (size_t)NEDGES * 4;
    float* xs        = (float*)w;                  w += (size_t)NNODES * 8 * 4;
    float* aggX      = (float*)w;                  w += (size_t)NNODES * 8 * 4;
    float* bufH      = (float*)w;                  w += (size_t)NNODES * 64 * 4;
    float* bufG      = (float*)w;                  w += (size_t)NNODES * 64 * 4;
    int*   tmp_dst   = (int*)bufG;                 // alias: NEDGES ints
    int*   tmp_src   = ((int*)bufG) + NEDGES;      // alias: NEDGES ints
    // total ~73 MB (round-1 version used 90MB successfully)

    const int B = 256;
    int gE    = (NEDGES + B - 1) / B;
    int gZ    = (NB * PAD + B - 1) / B;
    int gN2   = (NNODES * 2  + B - 1) / B;
    int gN64  = (NNODES * 64 + B - 1) / B;
    int gN112 = (NNODES * 112 + B - 1) / B;
    int gG8   = (NNODES * 2  + B - 1) / B;
    int gG64  = (NNODES * 16 + B - 1) / B;

    // --- CSR build ---
    bzero_kernel <<<gZ, B, 0, stream>>>(bcnt);
    bcount_kernel<<<gE, B, 0, stream>>>(dst, bcnt);
    bscan_kernel <<<1, 1024, 0, stream>>>(bcnt, bstart, bcur);
    bfill_kernel <<<gE, B, 0, stream>>>(src, dst, bcur, tmp_dst, tmp_src);
    bhist_kernel <<<NB, B, 0, stream>>>(tmp_dst, bstart, cnt);
    scan1_kernel <<<NBLK, 256, 0, stream>>>(cnt, row_start, bsum);
    scan2_kernel <<<1, 512, 0, stream>>>(bsum);
    scan3_kernel <<<NBLK, 256, 0, stream>>>(row_start, bsum, cursor, cnt, dinv);
    place_kernel <<<gE, B, 0, stream>>>(tmp_dst, tmp_src, cursor, csr_src);

    // --- layer 1: aggregate x (8-dim), then 8->64, ReLU, scale ---
    prescale_kernel<<<gN2, B, 0, stream>>>(x, dinv, xs);
    gather_kernel<8><<<gG8, B, 0, stream>>>(xs, row_start, csr_src, aggX);
    transform_kernel<8, 64, true, true><<<gN64, B, 0, stream>>>(aggX, dinv, W1, b1, bufH);

    // --- layer 2: aggregate hs1 (64-dim), then 64->64, ReLU, scale ---
    gather_kernel<64><<<gG64, B, 0, stream>>>(bufH, row_start, csr_src, bufG);
    transform_kernel<64, 64, true, true><<<gN64, B, 0, stream>>>(bufG, dinv, W2, b2, bufH);

    // --- layer 3: aggregate hs2 (64-dim), then 64->112, no ReLU, no scale ---
    gather_kernel<64><<<gG64, B, 0, stream>>>(bufH, row_start, csr_src, bufG);
    transform_kernel<64, 112, false, false><<<gN112, B, 0, stream>>>(bufG, dinv, W3, b3, out);
}

// Round 6
// 905.904 us; speedup vs baseline: 1.2621x; 1.2621x over previous
//
#include <hip/hip_runtime.h>

// GCN: N=100000 nodes, E=3200000 edges, dims 8 -> 64 -> 64 -> 112
//
// Algebra: per layer  agg[i] = hs[i] + sum_{j->i} hs[j]   (hs pre-scaled by dinv)
//                     t      = (dinv[i]*agg[i]) @ W + b
//                     hs_out = relu(t)*dinv[i]  (final layer: t raw)
// Layer 1 aggregates the 8-dim input; layers 2/3 aggregate 64-dim states.
//
// CSR build: bucket edges by dst>>7 (clustered append), per-bucket LDS
// histogram -> degrees, global scan -> row_start/cursor/dinv, clustered place.
// Transform: register-blocked thread-per-node GEMM; W in LDS read at
// wave-uniform addresses (broadcast, conflict-free), 16 accumulators ILP.

#define NNODES 100000
#define NEDGES 3200000
#define BW     128                          // nodes per bucket (dst >> 7)
#define NB     ((NNODES + BW - 1) / BW)     // 782 buckets
#define PAD    16                           // counter stride (ints) = 64B line
#define NBLK   ((NNODES + 255) / 256)       // 391 scan blocks

// ---------------- CSR build ----------------

__global__ void bzero_kernel(int* __restrict__ bcnt) {
    int i = blockIdx.x * blockDim.x + threadIdx.x;
    if (i < NB * PAD) bcnt[i] = 0;
}

__global__ void bcount_kernel(const int* __restrict__ dst, int* __restrict__ bcnt) {
    int e = blockIdx.x * blockDim.x + threadIdx.x;
    if (e < NEDGES) atomicAdd(&bcnt[(dst[e] >> 7) * PAD], 1);
}

// single-block exclusive scan of NB bucket counts -> bstart, bcur
__global__ void bscan_kernel(const int* __restrict__ bcnt, int* __restrict__ bstart,
                             int* __restrict__ bcur) {
    __shared__ int sh[1024];
    int v = (threadIdx.x < NB) ? bcnt[threadIdx.x * PAD] : 0;
    sh[threadIdx.x] = v;
    __syncthreads();
    for (int off = 1; off < 1024; off <<= 1) {
        int t = (threadIdx.x >= off) ? sh[threadIdx.x - off] : 0;
        __syncthreads();
        sh[threadIdx.x] += t;
        __syncthreads();
    }
    if (threadIdx.x < NB) {
        int e = sh[threadIdx.x] - v;       // exclusive
        bstart[threadIdx.x] = e;
        bcur[threadIdx.x * PAD] = e;
    }
    if (threadIdx.x == 0) bstart[NB] = NEDGES;
}

// append (dst,src) into the bucket's contiguous segment; writes cluster
__global__ void bfill_kernel(const int* __restrict__ src, const int* __restrict__ dst,
                             int* __restrict__ bcur,
                             int* __restrict__ tmp_dst, int* __restrict__ tmp_src) {
    int e = blockIdx.x * blockDim.x + threadIdx.x;
    if (e < NEDGES) {
        int d = dst[e];
        int p = atomicAdd(&bcur[(d >> 7) * PAD], 1);
        tmp_dst[p] = d;
        tmp_src[p] = src[e];
    }
}

// one block per bucket: LDS histogram of the bucket segment -> coalesced cnt[]
__global__ void bhist_kernel(const int* __restrict__ tmp_dst, const int* __restrict__ bstart,
                             int* __restrict__ cnt) {
    __shared__ int c[BW];
    int b   = blockIdx.x;
    int lo  = b * BW;
    int beg = bstart[b], end = bstart[b + 1];

    for (int t = threadIdx.x; t < BW; t += blockDim.x) c[t] = 0;
    __syncthreads();
    for (int k = beg + threadIdx.x; k < end; k += blockDim.x)
        atomicAdd(&c[tmp_dst[k] - lo], 1);
    __syncthreads();
    for (int t = threadIdx.x; t < BW; t += blockDim.x) {
        int i = lo + t;
        if (i < NNODES) cnt[i] = c[t];
    }
}

// ---- global scan chain ----

__global__ void scan1_kernel(const int* __restrict__ cnt, int* __restrict__ excl,
                             int* __restrict__ bsum) {
    __shared__ int sh[256];
    int i = blockIdx.x * 256 + threadIdx.x;
    int v = (i < NNODES) ? cnt[i] : 0;
    sh[threadIdx.x] = v;
    __syncthreads();
    for (int off = 1; off < 256; off <<= 1) {
        int t = (threadIdx.x >= off) ? sh[threadIdx.x - off] : 0;
        __syncthreads();
        sh[threadIdx.x] += t;
        __syncthreads();
    }
    if (i < NNODES) excl[i] = sh[threadIdx.x] - v;   // exclusive
    if (threadIdx.x == 255) bsum[blockIdx.x] = sh[255];
}

__global__ void scan2_kernel(int* __restrict__ bsum) {
    __shared__ int sh[512];
    int v = (threadIdx.x < NBLK) ? bsum[threadIdx.x] : 0;
    sh[threadIdx.x] = v;
    __syncthreads();
    for (int off = 1; off < 512; off <<= 1) {
        int t = (threadIdx.x >= off) ? sh[threadIdx.x - off] : 0;
        __syncthreads();
        sh[threadIdx.x] += t;
        __syncthreads();
    }
    if (threadIdx.x < NBLK) bsum[threadIdx.x] = sh[threadIdx.x] - v;
}

__global__ void scan3_kernel(int* __restrict__ row_start, const int* __restrict__ bsum,
                             int* __restrict__ cursor, const int* __restrict__ cnt,
                             float* __restrict__ dinv) {
    int i = blockIdx.x * 256 + threadIdx.x;
    if (i < NNODES) {
        int r = row_start[i] + bsum[blockIdx.x];
        row_start[i] = r;
        cursor[i] = r;
        dinv[i] = rsqrtf((float)cnt[i] + 1.0f);
    }
    if (i == 0) row_start[NNODES] = NEDGES;
}

// linear pass over bucket-ordered edges: cursor atomics + csr writes clustered
__global__ void place_kernel(const int* __restrict__ tmp_dst, const int* __restrict__ tmp_src,
                             int* __restrict__ cursor, int* __restrict__ csr_src) {
    int e = blockIdx.x * blockDim.x + threadIdx.x;
    if (e < NEDGES) {
        int d = tmp_dst[e];
        int pos = atomicAdd(&cursor[d], 1);
        csr_src[pos] = tmp_src[e];
    }
}

// ---------------- GCN layers ----------------

// xs[i][:] = x[i][:] * dinv[i]   (8 floats per node = 2 float4)
__global__ void prescale_kernel(const float* __restrict__ x, const float* __restrict__ dinv,
                                float* __restrict__ xs) {
    int idx = blockIdx.x * blockDim.x + threadIdx.x;
    if (idx >= NNODES * 2) return;
    float di = dinv[idx >> 1];
    float4 v = ((const float4*)x)[idx];
    v.x *= di; v.y *= di; v.z *= di; v.w *= di;
    ((float4*)xs)[idx] = v;
}

// agg[i][:] = hs[i][:] + sum_{j in N(i)} hs[j][:]  (thread owns one float4)
template<int F>
__global__ void gather_kernel(const float* __restrict__ hs, const int* __restrict__ row_start,
                              const int* __restrict__ csr_src, float* __restrict__ agg) {
    constexpr int NQ = F / 4;
    int idx = blockIdx.x * blockDim.x + threadIdx.x;
    if (idx >= NNODES * NQ) return;
    int i = idx / NQ;
    int q = idx % NQ;

    const float4* t4 = (const float4*)hs;
    float4 acc = t4[i * NQ + q];              // self-loop
    int beg = row_start[i], end = row_start[i + 1];
    for (int k = beg; k < end; ++k) {
        int s = csr_src[k];
        float4 v = t4[s * NQ + q];
        acc.x += v.x; acc.y += v.y; acc.z += v.z; acc.w += v.w;
    }
    ((float4*)agg)[i * NQ + q] = acc;
}

// out[i][:] = post( dinv[i] * (agg[i][:] @ W) + b )
// thread-per-node, row in registers, 16 accumulators per f-chunk,
// W read from LDS at wave-uniform addresses (broadcast, conflict-free)
template<int FIN, int FOUT, bool RELU, bool SCALE>
__global__ __launch_bounds__(256) void transform_kernel(
        const float* __restrict__ agg, const float* __restrict__ dinv,
        const float* __restrict__ W, const float* __restrict__ b,
        float* __restrict__ out) {
    __shared__ float Ws[FIN * FOUT];
    __shared__ float bs[FOUT];
    for (int t = threadIdx.x; t < FIN * FOUT; t += 256) Ws[t] = W[t];
    for (int t = threadIdx.x; t < FOUT; t += 256) bs[t] = b[t];
    __syncthreads();

    int i = blockIdx.x * 256 + threadIdx.x;
    if (i >= NNODES) return;

    const float4* row4 = (const float4*)(agg + (size_t)i * FIN);
    float4* out4 = (float4*)(out + (size_t)i * FOUT);
    float di = dinv[i];

    constexpr int NC = FOUT / 16;
    for (int c = 0; c < NC; ++c) {
        float4 a0 = make_float4(0.f, 0.f, 0.f, 0.f), a1 = a0, a2 = a0, a3 = a0;
        const float* wbase = Ws + c * 16;
#define FMA16(RV, KK) { const float4* wq = (const float4*)(wbase + (KK) * FOUT);     \
        float4 w0 = wq[0], w1 = wq[1], w2 = wq[2], w3 = wq[3];                       \
        a0.x += (RV)*w0.x; a0.y += (RV)*w0.y; a0.z += (RV)*w0.z; a0.w += (RV)*w0.w;  \
        a1.x += (RV)*w1.x; a1.y += (RV)*w1.y; a1.z += (RV)*w1.z; a1.w += (RV)*w1.w;  \
        a2.x += (RV)*w2.x; a2.y += (RV)*w2.y; a2.z += (RV)*w2.z; a2.w += (RV)*w2.w;  \
        a3.x += (RV)*w3.x; a3.y += (RV)*w3.y; a3.z += (RV)*w3.z; a3.w += (RV)*w3.w; }
#pragma unroll
        for (int k4 = 0; k4 < FIN / 4; ++k4) {
            float4 rv = row4[k4];
            FMA16(rv.x, 4 * k4 + 0)
            FMA16(rv.y, 4 * k4 + 1)
            FMA16(rv.z, 4 * k4 + 2)
            FMA16(rv.w, 4 * k4 + 3)
        }
#undef FMA16
        const float4* bq = (const float4*)(bs + c * 16);
        float4 b0 = bq[0], b1 = bq[1], b2 = bq[2], b3 = bq[3];
#define POST(A, B) { A.x = A.x * di + B.x; A.y = A.y * di + B.y;                     \
        A.z = A.z * di + B.z; A.w = A.w * di + B.w;                                  \
        if (RELU) { A.x = fmaxf(A.x, 0.f); A.y = fmaxf(A.y, 0.f);                    \
                    A.z = fmaxf(A.z, 0.f); A.w = fmaxf(A.w, 0.f); }                  \
        if (SCALE) { A.x *= di; A.y *= di; A.z *= di; A.w *= di; } }
        POST(a0, b0) POST(a1, b1) POST(a2, b2) POST(a3, b3)
#undef POST
        out4[c * 4 + 0] = a0;
        out4[c * 4 + 1] = a1;
        out4[c * 4 + 2] = a2;
        out4[c * 4 + 3] = a3;
    }
}

extern "C" void kernel_launch(void* const* d_in, const int* in_sizes, int n_in,
                              void* d_out, int out_size, void* d_ws, size_t ws_size,
                              hipStream_t stream) {
    const float* x  = (const float*)d_in[0];
    const int*   ei = (const int*)d_in[1];
    const float* W1 = (const float*)d_in[2];
    const float* b1 = (const float*)d_in[3];
    const float* W2 = (const float*)d_in[4];
    const float* b2 = (const float*)d_in[5];
    const float* W3 = (const float*)d_in[6];
    const float* b3 = (const float*)d_in[7];

    const int* src = ei;            // edge_index[0]
    const int* dst = ei + NEDGES;   // edge_index[1]

    float* out = (float*)d_out;     // N*112

    // workspace layout (16B-aligned chunks). tmp_dst/tmp_src alias bufG.
    char* w = (char*)d_ws;
    int*   bcnt      = (int*)w;                    w += NB * PAD * 4;
    int*   bcur      = (int*)w;                    w += NB * PAD * 4;
    int*   bstart    = (int*)w;                    w += ((NB + 1 + 3) / 4) * 16;
    int*   cnt       = (int*)w;                    w += ((NNODES + 3) / 4) * 16;
    int*   row_start = (int*)w;                    w += ((NNODES + 1 + 3) / 4) * 16;
    int*   cursor    = (int*)w;                    w += ((NNODES + 3) / 4) * 16;
    int*   bsum      = (int*)w;                    w += 512 * 4;
    float* dinv      = (float*)w;                  w += ((NNODES + 3) / 4) * 16;
    int*   csr_src   = (int*)w;                    w += (size_t)NEDGES * 4;
    float* xs        = (float*)w;                  w += (size_t)NNODES * 8 * 4;
    float* aggX      = (float*)w;                  w += (size_t)NNODES * 8 * 4;
    float* bufH      = (float*)w;                  w += (size_t)NNODES * 64 * 4;
    float* bufG      = (float*)w;                  w += (size_t)NNODES * 64 * 4;
    int*   tmp_dst   = (int*)bufG;                 // alias: NEDGES ints
    int*   tmp_src   = ((int*)bufG) + NEDGES;      // alias: NEDGES ints

    const int B = 256;
    int gE    = (NEDGES + B - 1) / B;
    int gZ    = (NB * PAD + B - 1) / B;
    int gN2   = (NNODES * 2  + B - 1) / B;
    int gT    = (NNODES + 255) / 256;              // transform: thread-per-node
    int gG8   = (NNODES * 2  + B - 1) / B;
    int gG64  = (NNODES * 16 + B - 1) / B;

    // --- CSR build ---
    bzero_kernel <<<gZ, B, 0, stream>>>(bcnt);
    bcount_kernel<<<gE, B, 0, stream>>>(dst, bcnt);
    bscan_kernel <<<1, 1024, 0, stream>>>(bcnt, bstart, bcur);
    bfill_kernel <<<gE, B, 0, stream>>>(src, dst, bcur, tmp_dst, tmp_src);
    bhist_kernel <<<NB, B, 0, stream>>>(tmp_dst, bstart, cnt);
    scan1_kernel <<<NBLK, 256, 0, stream>>>(cnt, row_start, bsum);
    scan2_kernel <<<1, 512, 0, stream>>>(bsum);
    scan3_kernel <<<NBLK, 256, 0, stream>>>(row_start, bsum, cursor, cnt, dinv);
    place_kernel <<<gE, B, 0, stream>>>(tmp_dst, tmp_src, cursor, csr_src);

    // --- layer 1: aggregate x (8-dim), then 8->64, ReLU, scale ---
    prescale_kernel<<<gN2, B, 0, stream>>>(x, dinv, xs);
    gather_kernel<8><<<gG8, B, 0, stream>>>(xs, row_start, csr_src, aggX);
    transform_kernel<8, 64, true, true><<<gT, 256, 0, stream>>>(aggX, dinv, W1, b1, bufH);

    // --- layer 2: aggregate hs1 (64-dim), then 64->64, ReLU, scale ---
    gather_kernel<64><<<gG64, B, 0, stream>>>(bufH, row_start, csr_src, bufG);
    transform_kernel<64, 64, true, true><<<gT, 256, 0, stream>>>(bufG, dinv, W2, b2, bufH);

    // --- layer 3: aggregate hs2 (64-dim), then 64->112, no ReLU, no scale ---
    gather_kernel<64><<<gG64, B, 0, stream>>>(bufH, row_start, csr_src, bufG);
    transform_kernel<64, 112, false, false><<<gT, 256, 0, stream>>>(bufG, dinv, W3, b3, out);
}

// Round 7
// 774.606 us; speedup vs baseline: 1.4761x; 1.1695x over previous
//
#include <hip/hip_runtime.h>

// GCN: N=100000 nodes, E=3200000 edges, dims 8 -> 64 -> 64 -> 112
//
// Algebra: per layer  agg[i] = hs[i] + sum_{j->i} hs[j]   (hs pre-scaled by dinv)
//                     t      = (dinv[i]*agg[i]) @ W + b
//                     hs_out = relu(t)*dinv[i]  (final layer: t raw)
// Layer 1 aggregates the 8-dim input; layers 2/3 aggregate 64-dim states.
//
// CSR build: bucket edges by dst>>7 with 8 XCD-private sub-segments per bucket
// (key = blockIdx&7; deterministic and matches round-robin block->XCD dispatch),
// so every tmp cache line is written by ONE XCD (kills the 9x cross-XCD
// partial-line write amplification seen in rocprof). tmp is packed u64.
// Then per-bucket LDS histogram -> degrees, global scan -> row_start/dinv,
// and per-bucket placement with LDS cursors (csr writes single-XCD too).

#define NNODES 100000
#define NEDGES 3200000
#define BW     128                          // nodes per bucket (dst >> 7)
#define NB     ((NNODES + BW - 1) / BW)     // 782 buckets
#define NSUB   8                            // XCD-private sub-buckets
#define PAD    16                           // counter stride (ints) = 64B line
#define NBLK   ((NNODES + 255) / 256)       // 391 scan blocks

typedef unsigned long long u64;

// ---------------- CSR build ----------------

__global__ void bzero_kernel(int* __restrict__ bcnt) {
    int i = blockIdx.x * blockDim.x + threadIdx.x;
    if (i < NB * NSUB * PAD) bcnt[i] = 0;
}

// count into (bucket, xcd) sub-counter; each counter hit by one XCD only
__global__ void bcount_kernel(const int* __restrict__ dst, int* __restrict__ bcnt) {
    int e = blockIdx.x * blockDim.x + threadIdx.x;
    int xc = blockIdx.x & (NSUB - 1);
    if (e < NEDGES) atomicAdd(&bcnt[((dst[e] >> 7) * NSUB + xc) * PAD], 1);
}

// single-block scan: thread b sums its 8 sub-counts, block-scan over buckets,
// then writes 8 sub-cursors (b-major layout => bucket range stays contiguous)
__global__ void bscan_kernel(const int* __restrict__ bcnt, int* __restrict__ bstart,
                             int* __restrict__ bcur) {
    __shared__ int sh[1024];
    int sub[NSUB];
    int tot = 0;
    if (threadIdx.x < NB) {
#pragma unroll
        for (int xcd = 0; xcd < NSUB; ++xcd) {
            sub[xcd] = bcnt[(threadIdx.x * NSUB + xcd) * PAD];
            tot += sub[xcd];
        }
    }
    sh[threadIdx.x] = (threadIdx.x < NB) ? tot : 0;
    __syncthreads();
    for (int off = 1; off < 1024; off <<= 1) {
        int t = (threadIdx.x >= off) ? sh[threadIdx.x - off] : 0;
        __syncthreads();
        sh[threadIdx.x] += t;
        __syncthreads();
    }
    if (threadIdx.x < NB) {
        int base = sh[threadIdx.x] - tot;      // exclusive over buckets
        bstart[threadIdx.x] = base;
#pragma unroll
        for (int xcd = 0; xcd < NSUB; ++xcd) {
            bcur[(threadIdx.x * NSUB + xcd) * PAD] = base;
            base += sub[xcd];
        }
    }
    if (threadIdx.x == 0) bstart[NB] = NEDGES;
}

// append packed (dst,src) into this block's XCD-private sub-segment
__global__ void bfill_kernel(const int* __restrict__ src, const int* __restrict__ dst,
                             int* __restrict__ bcur, u64* __restrict__ tmp) {
    int e = blockIdx.x * blockDim.x + threadIdx.x;
    int xc = blockIdx.x & (NSUB - 1);
    if (e < NEDGES) {
        int d = dst[e];
        int p = atomicAdd(&bcur[((d >> 7) * NSUB + xc) * PAD], 1);
        tmp[p] = ((u64)(unsigned)d << 32) | (unsigned)src[e];
    }
}

// one block per bucket: LDS histogram of the bucket segment -> coalesced cnt[]
__global__ void bhist_kernel(const u64* __restrict__ tmp, const int* __restrict__ bstart,
                             int* __restrict__ cnt) {
    __shared__ int c[BW];
    int b   = blockIdx.x;
    int lo  = b * BW;
    int beg = bstart[b], end = bstart[b + 1];

    for (int t = threadIdx.x; t < BW; t += blockDim.x) c[t] = 0;
    __syncthreads();
    for (int k = beg + threadIdx.x; k < end; k += blockDim.x)
        atomicAdd(&c[(int)(tmp[k] >> 32) - lo], 1);
    __syncthreads();
    for (int t = threadIdx.x; t < BW; t += blockDim.x) {
        int i = lo + t;
        if (i < NNODES) cnt[i] = c[t];
    }
}

// ---- global scan chain ----

__global__ void scan1_kernel(const int* __restrict__ cnt, int* __restrict__ excl,
                             int* __restrict__ bsum) {
    __shared__ int sh[256];
    int i = blockIdx.x * 256 + threadIdx.x;
    int v = (i < NNODES) ? cnt[i] : 0;
    sh[threadIdx.x] = v;
    __syncthreads();
    for (int off = 1; off < 256; off <<= 1) {
        int t = (threadIdx.x >= off) ? sh[threadIdx.x - off] : 0;
        __syncthreads();
        sh[threadIdx.x] += t;
        __syncthreads();
    }
    if (i < NNODES) excl[i] = sh[threadIdx.x] - v;   // exclusive
    if (threadIdx.x == 255) bsum[blockIdx.x] = sh[255];
}

__global__ void scan2_kernel(int* __restrict__ bsum) {
    __shared__ int sh[512];
    int v = (threadIdx.x < NBLK) ? bsum[threadIdx.x] : 0;
    sh[threadIdx.x] = v;
    __syncthreads();
    for (int off = 1; off < 512; off <<= 1) {
        int t = (threadIdx.x >= off) ? sh[threadIdx.x - off] : 0;
        __syncthreads();
        sh[threadIdx.x] += t;
        __syncthreads();
    }
    if (threadIdx.x < NBLK) bsum[threadIdx.x] = sh[threadIdx.x] - v;
}

__global__ void scan3_kernel(int* __restrict__ row_start, const int* __restrict__ bsum,
                             const int* __restrict__ cnt, float* __restrict__ dinv) {
    int i = blockIdx.x * 256 + threadIdx.x;
    if (i < NNODES) {
        row_start[i] += bsum[blockIdx.x];
        dinv[i] = rsqrtf((float)cnt[i] + 1.0f);
    }
    if (i == 0) row_start[NNODES] = NEDGES;
}

// one block per bucket: LDS cursors seeded from row_start; all csr writes
// for this bucket come from one CU (one XCD) -> no cross-XCD partial lines
__global__ void place_kernel(const u64* __restrict__ tmp, const int* __restrict__ bstart,
                             const int* __restrict__ row_start, int* __restrict__ csr_src) {
    __shared__ int cur[BW];
    int b   = blockIdx.x;
    int lo  = b * BW;
    int beg = bstart[b], end = bstart[b + 1];

    for (int t = threadIdx.x; t < BW; t += blockDim.x) {
        int i = lo + t;
        cur[t] = (i < NNODES) ? row_start[i] : 0;
    }
    __syncthreads();
    for (int k = beg + threadIdx.x; k < end; k += blockDim.x) {
        u64 pk = tmp[k];
        int d = (int)(pk >> 32);
        int s = (int)(pk & 0xffffffffu);
        int pos = atomicAdd(&cur[d - lo], 1);
        csr_src[pos] = s;
    }
}

// ---------------- GCN layers ----------------

// xs[i][:] = x[i][:] * dinv[i]   (8 floats per node = 2 float4)
__global__ void prescale_kernel(const float* __restrict__ x, const float* __restrict__ dinv,
                                float* __restrict__ xs) {
    int idx = blockIdx.x * blockDim.x + threadIdx.x;
    if (idx >= NNODES * 2) return;
    float di = dinv[idx >> 1];
    float4 v = ((const float4*)x)[idx];
    v.x *= di; v.y *= di; v.z *= di; v.w *= di;
    ((float4*)xs)[idx] = v;
}

// agg[i][:] = hs[i][:] + sum_{j in N(i)} hs[j][:]  (thread owns one float4)
template<int F>
__global__ void gather_kernel(const float* __restrict__ hs, const int* __restrict__ row_start,
                              const int* __restrict__ csr_src, float* __restrict__ agg) {
    constexpr int NQ = F / 4;
    int idx = blockIdx.x * blockDim.x + threadIdx.x;
    if (idx >= NNODES * NQ) return;
    int i = idx / NQ;
    int q = idx % NQ;

    const float4* t4 = (const float4*)hs;
    float4 acc = t4[i * NQ + q];              // self-loop
    int beg = row_start[i], end = row_start[i + 1];
    for (int k = beg; k < end; ++k) {
        int s = csr_src[k];
        float4 v = t4[s * NQ + q];
        acc.x += v.x; acc.y += v.y; acc.z += v.z; acc.w += v.w;
    }
    ((float4*)agg)[i * NQ + q] = acc;
}

// out[i][:] = post( dinv[i] * (agg[i][:] @ W) + b )
// thread-per-node, row in registers, 16 accumulators per f-chunk,
// W read from LDS at wave-uniform addresses (broadcast, conflict-free)
template<int FIN, int FOUT, bool RELU, bool SCALE>
__global__ __launch_bounds__(256) void transform_kernel(
        const float* __restrict__ agg, const float* __restrict__ dinv,
        const float* __restrict__ W, const float* __restrict__ b,
        float* __restrict__ out) {
    __shared__ float Ws[FIN * FOUT];
    __shared__ float bs[FOUT];
    for (int t = threadIdx.x; t < FIN * FOUT; t += 256) Ws[t] = W[t];
    for (int t = threadIdx.x; t < FOUT; t += 256) bs[t] = b[t];
    __syncthreads();

    int i = blockIdx.x * 256 + threadIdx.x;
    if (i >= NNODES) return;

    const float4* row4 = (const float4*)(agg + (size_t)i * FIN);
    float4* out4 = (float4*)(out + (size_t)i * FOUT);
    float di = dinv[i];

    constexpr int NC = FOUT / 16;
    for (int c = 0; c < NC; ++c) {
        float4 a0 = make_float4(0.f, 0.f, 0.f, 0.f), a1 = a0, a2 = a0, a3 = a0;
        const float* wbase = Ws + c * 16;
#define FMA16(RV, KK) { const float4* wq = (const float4*)(wbase + (KK) * FOUT);     \
        float4 w0 = wq[0], w1 = wq[1], w2 = wq[2], w3 = wq[3];                       \
        a0.x += (RV)*w0.x; a0.y += (RV)*w0.y; a0.z += (RV)*w0.z; a0.w += (RV)*w0.w;  \
        a1.x += (RV)*w1.x; a1.y += (RV)*w1.y; a1.z += (RV)*w1.z; a1.w += (RV)*w1.w;  \
        a2.x += (RV)*w2.x; a2.y += (RV)*w2.y; a2.z += (RV)*w2.z; a2.w += (RV)*w2.w;  \
        a3.x += (RV)*w3.x; a3.y += (RV)*w3.y; a3.z += (RV)*w3.z; a3.w += (RV)*w3.w; }
#pragma unroll
        for (int k4 = 0; k4 < FIN / 4; ++k4) {
            float4 rv = row4[k4];
            FMA16(rv.x, 4 * k4 + 0)
            FMA16(rv.y, 4 * k4 + 1)
            FMA16(rv.z, 4 * k4 + 2)
            FMA16(rv.w, 4 * k4 + 3)
        }
#undef FMA16
        const float4* bq = (const float4*)(bs + c * 16);
        float4 b0 = bq[0], b1 = bq[1], b2 = bq[2], b3 = bq[3];
#define POST(A, B) { A.x = A.x * di + B.x; A.y = A.y * di + B.y;                     \
        A.z = A.z * di + B.z; A.w = A.w * di + B.w;                                  \
        if (RELU) { A.x = fmaxf(A.x, 0.f); A.y = fmaxf(A.y, 0.f);                    \
                    A.z = fmaxf(A.z, 0.f); A.w = fmaxf(A.w, 0.f); }                  \
        if (SCALE) { A.x *= di; A.y *= di; A.z *= di; A.w *= di; } }
        POST(a0, b0) POST(a1, b1) POST(a2, b2) POST(a3, b3)
#undef POST
        out4[c * 4 + 0] = a0;
        out4[c * 4 + 1] = a1;
        out4[c * 4 + 2] = a2;
        out4[c * 4 + 3] = a3;
    }
}

extern "C" void kernel_launch(void* const* d_in, const int* in_sizes, int n_in,
                              void* d_out, int out_size, void* d_ws, size_t ws_size,
                              hipStream_t stream) {
    const float* x  = (const float*)d_in[0];
    const int*   ei = (const int*)d_in[1];
    const float* W1 = (const float*)d_in[2];
    const float* b1 = (const float*)d_in[3];
    const float* W2 = (const float*)d_in[4];
    const float* b2 = (const float*)d_in[5];
    const float* W3 = (const float*)d_in[6];
    const float* b3 = (const float*)d_in[7];

    const int* src = ei;            // edge_index[0]
    const int* dst = ei + NEDGES;   // edge_index[1]

    float* out = (float*)d_out;     // N*112

    // workspace layout (16B-aligned chunks). tmp aliases bufG (both 25.6 MB);
    // tmp is dead before the first 64-dim gather writes bufG.
    char* w = (char*)d_ws;
    int*   bcnt      = (int*)w;                    w += NB * NSUB * PAD * 4;   // 400 KB
    int*   bcur      = (int*)w;                    w += NB * NSUB * PAD * 4;   // 400 KB
    int*   bstart    = (int*)w;                    w += ((NB + 1 + 3) / 4) * 16;
    int*   cnt       = (int*)w;                    w += ((NNODES + 3) / 4) * 16;
    int*   row_start = (int*)w;                    w += ((NNODES + 1 + 3) / 4) * 16;
    int*   bsum      = (int*)w;                    w += 512 * 4;
    float* dinv      = (float*)w;                  w += ((NNODES + 3) / 4) * 16;
    int*   csr_src   = (int*)w;                    w += (size_t)NEDGES * 4;
    float* xs        = (float*)w;                  w += (size_t)NNODES * 8 * 4;
    float* aggX      = (float*)w;                  w += (size_t)NNODES * 8 * 4;
    float* bufH      = (float*)w;                  w += (size_t)NNODES * 64 * 4;
    float* bufG      = (float*)w;                  w += (size_t)NNODES * 64 * 4;
    u64*   tmp       = (u64*)bufG;                 // alias: NEDGES u64

    const int B = 256;
    int gE    = (NEDGES + B - 1) / B;
    int gZ    = (NB * NSUB * PAD + B - 1) / B;
    int gN2   = (NNODES * 2  + B - 1) / B;
    int gT    = (NNODES + 255) / 256;              // transform: thread-per-node
    int gG8   = (NNODES * 2  + B - 1) / B;
    int gG64  = (NNODES * 16 + B - 1) / B;

    // --- CSR build ---
    bzero_kernel <<<gZ, B, 0, stream>>>(bcnt);
    bcount_kernel<<<gE, B, 0, stream>>>(dst, bcnt);
    bscan_kernel <<<1, 1024, 0, stream>>>(bcnt, bstart, bcur);
    bfill_kernel <<<gE, B, 0, stream>>>(src, dst, bcur, tmp);
    bhist_kernel <<<NB, B, 0, stream>>>(tmp, bstart, cnt);
    scan1_kernel <<<NBLK, 256, 0, stream>>>(cnt, row_start, bsum);
    scan2_kernel <<<1, 512, 0, stream>>>(bsum);
    scan3_kernel <<<NBLK, 256, 0, stream>>>(row_start, bsum, cnt, dinv);
    place_kernel <<<NB, B, 0, stream>>>(tmp, bstart, row_start, csr_src);

    // --- layer 1: aggregate x (8-dim), then 8->64, ReLU, scale ---
    prescale_kernel<<<gN2, B, 0, stream>>>(x, dinv, xs);
    gather_kernel<8><<<gG8, B, 0, stream>>>(xs, row_start, csr_src, aggX);
    transform_kernel<8, 64, true, true><<<gT, 256, 0, stream>>>(aggX, dinv, W1, b1, bufH);

    // --- layer 2: aggregate hs1 (64-dim), then 64->64, ReLU, scale ---
    gather_kernel<64><<<gG64, B, 0, stream>>>(bufH, row_start, csr_src, bufG);
    transform_kernel<64, 64, true, true><<<gT, 256, 0, stream>>>(bufG, dinv, W2, b2, bufH);

    // --- layer 3: aggregate hs2 (64-dim), then 64->112, no ReLU, no scale ---
    gather_kernel<64><<<gG64, B, 0, stream>>>(bufH, row_start, csr_src, bufG);
    transform_kernel<64, 112, false, false><<<gT, 256, 0, stream>>>(bufG, dinv, W3, b3, out);
}

// Round 8
// 746.436 us; speedup vs baseline: 1.5318x; 1.0377x over previous
//
#include <hip/hip_runtime.h>

// GCN: N=100000 nodes, E=3200000 edges, dims 8 -> 64 -> 64 -> 112
//
// Algebra: per layer  agg[i] = hs[i] + sum_{j->i} hs[j]   (hs pre-scaled by dinv)
//                     t      = (dinv[i]*agg[i]) @ W + b
//                     hs_out = relu(t)*dinv[i]  (final layer: t raw)
// Layer 1 aggregates the 8-dim input; layers 2/3 aggregate 64-dim states.
//
// CSR build: bucket edges by dst>>7 with 8 XCD-private sub-segments per bucket
// (key = blockIdx&7), so every tmp line is written by ONE XCD. Per-bucket LDS
// histogram -> degrees, global scan -> row_start/dinv, per-bucket LDS-cursor
// placement. Gather: 16 threads/node, 4-way unrolled neighbor loop with 4
// independent accumulators (quadruples outstanding loads; gather is MLP-bound).

#define NNODES 100000
#define NEDGES 3200000
#define BW     128                          // nodes per bucket (dst >> 7)
#define NB     ((NNODES + BW - 1) / BW)     // 782 buckets
#define NSUB   8                            // XCD-private sub-buckets
#define PAD    16                           // counter stride (ints) = 64B line
#define NBLK   ((NNODES + 255) / 256)       // 391 scan blocks

typedef unsigned long long u64;

// ---------------- CSR build ----------------

__global__ void bzero_kernel(int* __restrict__ bcnt) {
    int i = blockIdx.x * blockDim.x + threadIdx.x;
    if (i < NB * NSUB * PAD) bcnt[i] = 0;
}

// count into (bucket, xcd) sub-counter; each counter hit by one XCD only
__global__ void bcount_kernel(const int* __restrict__ dst, int* __restrict__ bcnt) {
    int e = blockIdx.x * blockDim.x + threadIdx.x;
    int xc = blockIdx.x & (NSUB - 1);
    if (e < NEDGES) atomicAdd(&bcnt[((dst[e] >> 7) * NSUB + xc) * PAD], 1);
}

// single-block scan: thread b sums its 8 sub-counts, block-scan over buckets,
// then writes 8 sub-cursors (b-major layout => bucket range stays contiguous)
__global__ void bscan_kernel(const int* __restrict__ bcnt, int* __restrict__ bstart,
                             int* __restrict__ bcur) {
    __shared__ int sh[1024];
    int sub[NSUB];
    int tot = 0;
    if (threadIdx.x < NB) {
#pragma unroll
        for (int xcd = 0; xcd < NSUB; ++xcd) {
            sub[xcd] = bcnt[(threadIdx.x * NSUB + xcd) * PAD];
            tot += sub[xcd];
        }
    }
    sh[threadIdx.x] = (threadIdx.x < NB) ? tot : 0;
    __syncthreads();
    for (int off = 1; off < 1024; off <<= 1) {
        int t = (threadIdx.x >= off) ? sh[threadIdx.x - off] : 0;
        __syncthreads();
        sh[threadIdx.x] += t;
        __syncthreads();
    }
    if (threadIdx.x < NB) {
        int base = sh[threadIdx.x] - tot;      // exclusive over buckets
        bstart[threadIdx.x] = base;
#pragma unroll
        for (int xcd = 0; xcd < NSUB; ++xcd) {
            bcur[(threadIdx.x * NSUB + xcd) * PAD] = base;
            base += sub[xcd];
        }
    }
    if (threadIdx.x == 0) bstart[NB] = NEDGES;
}

// append packed (dst,src) into this block's XCD-private sub-segment
__global__ void bfill_kernel(const int* __restrict__ src, const int* __restrict__ dst,
                             int* __restrict__ bcur, u64* __restrict__ tmp) {
    int e = blockIdx.x * blockDim.x + threadIdx.x;
    int xc = blockIdx.x & (NSUB - 1);
    if (e < NEDGES) {
        int d = dst[e];
        int p = atomicAdd(&bcur[((d >> 7) * NSUB + xc) * PAD], 1);
        tmp[p] = ((u64)(unsigned)d << 32) | (unsigned)src[e];
    }
}

// one block per bucket: LDS histogram of the bucket segment -> coalesced cnt[]
__global__ void bhist_kernel(const u64* __restrict__ tmp, const int* __restrict__ bstart,
                             int* __restrict__ cnt) {
    __shared__ int c[BW];
    int b   = blockIdx.x;
    int lo  = b * BW;
    int beg = bstart[b], end = bstart[b + 1];

    for (int t = threadIdx.x; t < BW; t += blockDim.x) c[t] = 0;
    __syncthreads();
    for (int k = beg + threadIdx.x; k < end; k += blockDim.x)
        atomicAdd(&c[(int)(tmp[k] >> 32) - lo], 1);
    __syncthreads();
    for (int t = threadIdx.x; t < BW; t += blockDim.x) {
        int i = lo + t;
        if (i < NNODES) cnt[i] = c[t];
    }
}

// ---- global scan chain ----

__global__ void scan1_kernel(const int* __restrict__ cnt, int* __restrict__ excl,
                             int* __restrict__ bsum) {
    __shared__ int sh[256];
    int i = blockIdx.x * 256 + threadIdx.x;
    int v = (i < NNODES) ? cnt[i] : 0;
    sh[threadIdx.x] = v;
    __syncthreads();
    for (int off = 1; off < 256; off <<= 1) {
        int t = (threadIdx.x >= off) ? sh[threadIdx.x - off] : 0;
        __syncthreads();
        sh[threadIdx.x] += t;
        __syncthreads();
    }
    if (i < NNODES) excl[i] = sh[threadIdx.x] - v;   // exclusive
    if (threadIdx.x == 255) bsum[blockIdx.x] = sh[255];
}

__global__ void scan2_kernel(int* __restrict__ bsum) {
    __shared__ int sh[512];
    int v = (threadIdx.x < NBLK) ? bsum[threadIdx.x] : 0;
    sh[threadIdx.x] = v;
    __syncthreads();
    for (int off = 1; off < 512; off <<= 1) {
        int t = (threadIdx.x >= off) ? sh[threadIdx.x - off] : 0;
        __syncthreads();
        sh[threadIdx.x] += t;
        __syncthreads();
    }
    if (threadIdx.x < NBLK) bsum[threadIdx.x] = sh[threadIdx.x] - v;
}

__global__ void scan3_kernel(int* __restrict__ row_start, const int* __restrict__ bsum,
                             const int* __restrict__ cnt, float* __restrict__ dinv) {
    int i = blockIdx.x * 256 + threadIdx.x;
    if (i < NNODES) {
        row_start[i] += bsum[blockIdx.x];
        dinv[i] = rsqrtf((float)cnt[i] + 1.0f);
    }
    if (i == 0) row_start[NNODES] = NEDGES;
}

// one block per bucket: LDS cursors seeded from row_start; all csr writes
// for this bucket come from one CU (one XCD) -> no cross-XCD partial lines
__global__ void place_kernel(const u64* __restrict__ tmp, const int* __restrict__ bstart,
                             const int* __restrict__ row_start, int* __restrict__ csr_src) {
    __shared__ int cur[BW];
    int b   = blockIdx.x;
    int lo  = b * BW;
    int beg = bstart[b], end = bstart[b + 1];

    for (int t = threadIdx.x; t < BW; t += blockDim.x) {
        int i = lo + t;
        cur[t] = (i < NNODES) ? row_start[i] : 0;
    }
    __syncthreads();
    for (int k = beg + threadIdx.x; k < end; k += blockDim.x) {
        u64 pk = tmp[k];
        int d = (int)(pk >> 32);
        int s = (int)(pk & 0xffffffffu);
        int pos = atomicAdd(&cur[d - lo], 1);
        csr_src[pos] = s;
    }
}

// ---------------- GCN layers ----------------

// xs[i][:] = x[i][:] * dinv[i]   (8 floats per node = 2 float4)
__global__ void prescale_kernel(const float* __restrict__ x, const float* __restrict__ dinv,
                                float* __restrict__ xs) {
    int idx = blockIdx.x * blockDim.x + threadIdx.x;
    if (idx >= NNODES * 2) return;
    float di = dinv[idx >> 1];
    float4 v = ((const float4*)x)[idx];
    v.x *= di; v.y *= di; v.z *= di; v.w *= di;
    ((float4*)xs)[idx] = v;
}

#define ACC4(A, V) { A.x += V.x; A.y += V.y; A.z += V.z; A.w += V.w; }

// agg[i][:] = hs[i][:] + sum_{j in N(i)} hs[j][:]  (thread owns one float4)
// 4-way unrolled neighbor loop, 4 independent accumulators -> 4 loads in flight
template<int F>
__global__ void gather_kernel(const float* __restrict__ hs, const int* __restrict__ row_start,
                              const int* __restrict__ csr_src, float* __restrict__ agg) {
    constexpr int NQ = F / 4;
    int idx = blockIdx.x * blockDim.x + threadIdx.x;
    if (idx >= NNODES * NQ) return;
    int i = idx / NQ;
    int q = idx % NQ;

    const float4* t4 = (const float4*)hs;
    float4 a0 = t4[i * NQ + q];               // self-loop
    float4 a1 = make_float4(0.f, 0.f, 0.f, 0.f), a2 = a1, a3 = a1;
    int beg = row_start[i], end = row_start[i + 1];
    int k = beg;
    for (; k + 4 <= end; k += 4) {
        int s0 = csr_src[k + 0];
        int s1 = csr_src[k + 1];
        int s2 = csr_src[k + 2];
        int s3 = csr_src[k + 3];
        float4 v0 = t4[s0 * NQ + q];
        float4 v1 = t4[s1 * NQ + q];
        float4 v2 = t4[s2 * NQ + q];
        float4 v3 = t4[s3 * NQ + q];
        ACC4(a0, v0) ACC4(a1, v1) ACC4(a2, v2) ACC4(a3, v3)
    }
    for (; k < end; ++k) {
        float4 v = t4[csr_src[k] * NQ + q];
        ACC4(a0, v)
    }
    ACC4(a0, a1) ACC4(a2, a3) ACC4(a0, a2)
    ((float4*)agg)[i * NQ + q] = a0;
}

// out[i][:] = post( dinv[i] * (agg[i][:] @ W) + b )
// thread-per-node, row in registers, 16 accumulators per f-chunk,
// W read from LDS at wave-uniform addresses (broadcast, conflict-free)
template<int FIN, int FOUT, bool RELU, bool SCALE>
__global__ __launch_bounds__(256) void transform_kernel(
        const float* __restrict__ agg, const float* __restrict__ dinv,
        const float* __restrict__ W, const float* __restrict__ b,
        float* __restrict__ out) {
    __shared__ float Ws[FIN * FOUT];
    __shared__ float bs[FOUT];
    for (int t = threadIdx.x; t < FIN * FOUT; t += 256) Ws[t] = W[t];
    for (int t = threadIdx.x; t < FOUT; t += 256) bs[t] = b[t];
    __syncthreads();

    int i = blockIdx.x * 256 + threadIdx.x;
    if (i >= NNODES) return;

    const float4* row4 = (const float4*)(agg + (size_t)i * FIN);
    float4* out4 = (float4*)(out + (size_t)i * FOUT);
    float di = dinv[i];

    constexpr int NC = FOUT / 16;
    for (int c = 0; c < NC; ++c) {
        float4 a0 = make_float4(0.f, 0.f, 0.f, 0.f), a1 = a0, a2 = a0, a3 = a0;
        const float* wbase = Ws + c * 16;
#define FMA16(RV, KK) { const float4* wq = (const float4*)(wbase + (KK) * FOUT);     \
        float4 w0 = wq[0], w1 = wq[1], w2 = wq[2], w3 = wq[3];                       \
        a0.x += (RV)*w0.x; a0.y += (RV)*w0.y; a0.z += (RV)*w0.z; a0.w += (RV)*w0.w;  \
        a1.x += (RV)*w1.x; a1.y += (RV)*w1.y; a1.z += (RV)*w1.z; a1.w += (RV)*w1.w;  \
        a2.x += (RV)*w2.x; a2.y += (RV)*w2.y; a2.z += (RV)*w2.z; a2.w += (RV)*w2.w;  \
        a3.x += (RV)*w3.x; a3.y += (RV)*w3.y; a3.z += (RV)*w3.z; a3.w += (RV)*w3.w; }
#pragma unroll
        for (int k4 = 0; k4 < FIN / 4; ++k4) {
            float4 rv = row4[k4];
            FMA16(rv.x, 4 * k4 + 0)
            FMA16(rv.y, 4 * k4 + 1)
            FMA16(rv.z, 4 * k4 + 2)
            FMA16(rv.w, 4 * k4 + 3)
        }
#undef FMA16
        const float4* bq = (const float4*)(bs + c * 16);
        float4 b0 = bq[0], b1 = bq[1], b2 = bq[2], b3 = bq[3];
#define POST(A, B) { A.x = A.x * di + B.x; A.y = A.y * di + B.y;                     \
        A.z = A.z * di + B.z; A.w = A.w * di + B.w;                                  \
        if (RELU) { A.x = fmaxf(A.x, 0.f); A.y = fmaxf(A.y, 0.f);                    \
                    A.z = fmaxf(A.z, 0.f); A.w = fmaxf(A.w, 0.f); }                  \
        if (SCALE) { A.x *= di; A.y *= di; A.z *= di; A.w *= di; } }
        POST(a0, b0) POST(a1, b1) POST(a2, b2) POST(a3, b3)
#undef POST
        out4[c * 4 + 0] = a0;
        out4[c * 4 + 1] = a1;
        out4[c * 4 + 2] = a2;
        out4[c * 4 + 3] = a3;
    }
}

extern "C" void kernel_launch(void* const* d_in, const int* in_sizes, int n_in,
                              void* d_out, int out_size, void* d_ws, size_t ws_size,
                              hipStream_t stream) {
    const float* x  = (const float*)d_in[0];
    const int*   ei = (const int*)d_in[1];
    const float* W1 = (const float*)d_in[2];
    const float* b1 = (const float*)d_in[3];
    const float* W2 = (const float*)d_in[4];
    const float* b2 = (const float*)d_in[5];
    const float* W3 = (const float*)d_in[6];
    const float* b3 = (const float*)d_in[7];

    const int* src = ei;            // edge_index[0]
    const int* dst = ei + NEDGES;   // edge_index[1]

    float* out = (float*)d_out;     // N*112

    // workspace layout (16B-aligned chunks). tmp aliases bufG (both 25.6 MB);
    // tmp is dead before the first 64-dim gather writes bufG.
    char* w = (char*)d_ws;
    int*   bcnt      = (int*)w;                    w += NB * NSUB * PAD * 4;   // 400 KB
    int*   bcur      = (int*)w;                    w += NB * NSUB * PAD * 4;   // 400 KB
    int*   bstart    = (int*)w;                    w += ((NB + 1 + 3) / 4) * 16;
    int*   cnt       = (int*)w;                    w += ((NNODES + 3) / 4) * 16;
    int*   row_start = (int*)w;                    w += ((NNODES + 1 + 3) / 4) * 16;
    int*   bsum      = (int*)w;                    w += 512 * 4;
    float* dinv      = (float*)w;                  w += ((NNODES + 3) / 4) * 16;
    int*   csr_src   = (int*)w;                    w += (size_t)NEDGES * 4;
    float* xs        = (float*)w;                  w += (size_t)NNODES * 8 * 4;
    float* aggX      = (float*)w;                  w += (size_t)NNODES * 8 * 4;
    float* bufH      = (float*)w;                  w += (size_t)NNODES * 64 * 4;
    float* bufG      = (float*)w;                  w += (size_t)NNODES * 64 * 4;
    u64*   tmp       = (u64*)bufG;                 // alias: NEDGES u64

    const int B = 256;
    int gE    = (NEDGES + B - 1) / B;
    int gZ    = (NB * NSUB * PAD + B - 1) / B;
    int gN2   = (NNODES * 2  + B - 1) / B;
    int gT    = (NNODES + 255) / 256;              // transform: thread-per-node
    int gG8   = (NNODES * 2  + B - 1) / B;
    int gG64  = (NNODES * 16 + B - 1) / B;

    // --- CSR build ---
    bzero_kernel <<<gZ, B, 0, stream>>>(bcnt);
    bcount_kernel<<<gE, B, 0, stream>>>(dst, bcnt);
    bscan_kernel <<<1, 1024, 0, stream>>>(bcnt, bstart, bcur);
    bfill_kernel <<<gE, B, 0, stream>>>(src, dst, bcur, tmp);
    bhist_kernel <<<NB, B, 0, stream>>>(tmp, bstart, cnt);
    scan1_kernel <<<NBLK, 256, 0, stream>>>(cnt, row_start, bsum);
    scan2_kernel <<<1, 512, 0, stream>>>(bsum);
    scan3_kernel <<<NBLK, 256, 0, stream>>>(row_start, bsum, cnt, dinv);
    place_kernel <<<NB, B, 0, stream>>>(tmp, bstart, row_start, csr_src);

    // --- layer 1: aggregate x (8-dim), then 8->64, ReLU, scale ---
    prescale_kernel<<<gN2, B, 0, stream>>>(x, dinv, xs);
    gather_kernel<8><<<gG8, B, 0, stream>>>(xs, row_start, csr_src, aggX);
    transform_kernel<8, 64, true, true><<<gT, 256, 0, stream>>>(aggX, dinv, W1, b1, bufH);

    // --- layer 2: aggregate hs1 (64-dim), then 64->64, ReLU, scale ---
    gather_kernel<64><<<gG64, B, 0, stream>>>(bufH, row_start, csr_src, bufG);
    transform_kernel<64, 64, true, true><<<gT, 256, 0, stream>>>(bufG, dinv, W2, b2, bufH);

    // --- layer 3: aggregate hs2 (64-dim), then 64->112, no ReLU, no scale ---
    gather_kernel<64><<<gG64, B, 0, stream>>>(bufH, row_start, csr_src, bufG);
    transform_kernel<64, 112, false, false><<<gT, 256, 0, stream>>>(bufG, dinv, W3, b3, out);
}